// Round 5
// baseline (202.102 us; speedup 1.0000x reference)
//
#include <hip/hip_runtime.h>
#include <math.h>

typedef _Float16 half8_t __attribute__((ext_vector_type(8)));
typedef _Float16 half4_t __attribute__((ext_vector_type(4)));
typedef _Float16 half2_t __attribute__((ext_vector_type(2)));
typedef float f32x4 __attribute__((ext_vector_type(4)));
typedef float f32x16 __attribute__((ext_vector_type(16)));
typedef unsigned int uint32x4 __attribute__((ext_vector_type(4)));

#define MFMA16(a, b, c) __builtin_amdgcn_mfma_f32_16x16x32_f16((a), (b), (c), 0, 0, 0)
#define MFMA32(a, b, c) __builtin_amdgcn_mfma_f32_32x32x16_f16((a), (b), (c), 0, 0, 0)

// log2(e) / sqrt(128): fold softmax scale AND exp->exp2 conversion into q.
#define SCALE_Q (0.08838834764831845f * 1.44269504088896340736f)

static __device__ inline unsigned int pkh(float a, float b) {
    half2_t h;
    h[0] = (_Float16)a;
    h[1] = (_Float16)b;
    return __builtin_bit_cast(unsigned int, h);
}

// ---------------------------------------------------------------------------
// Kernel 0: W [512][128] fp32  ->  Wt [128][512] fp16   (x3 for q,k,v)
// ---------------------------------------------------------------------------
__global__ __launch_bounds__(256) void wt_kernel(const float* __restrict__ Wq,
                                                 const float* __restrict__ Wk,
                                                 const float* __restrict__ Wv,
                                                 _Float16* __restrict__ WtAll) {
    int y = blockIdx.y;
    const float* W = (y == 0) ? Wq : (y == 1) ? Wk : Wv;
    int idx = blockIdx.x * 256 + threadIdx.x;
    int kk = idx >> 7;
    int d  = idx & 127;
    WtAll[y * 65536 + d * 512 + kk] = (_Float16)W[idx];
}

// ---------------------------------------------------------------------------
// Kernel 1: projection GEMM v2.  C[16384][128] = X[16384][512] @ W + b
// 64-row x 128-col blocks (768 blocks, 2 blocks/CU). X staged ONCE into LDS
// (fp16, granule-XOR swizzle for conflict-floor K-major reads); W^T B-frags
// stream straight from global (L2-resident, 384 KB); NO barriers in K-loop.
// ---------------------------------------------------------------------------
__global__ __launch_bounds__(256) void proj_kernel(
    const float* __restrict__ q_in, const float* __restrict__ k_in,
    const float* __restrict__ v_in, const _Float16* __restrict__ WtAll,
    const float* __restrict__ biasq, const float* __restrict__ biask,
    const float* __restrict__ biasv,
    _Float16* __restrict__ qbuf, _Float16* __restrict__ kbuf,
    _Float16* __restrict__ vtbuf) {
    int y = blockIdx.y;
    const float* x = (y == 0) ? q_in : (y == 1) ? k_in : v_in;
    const _Float16* Wt = WtAll + y * 65536;
    const float* bias = (y == 0) ? biasq : (y == 1) ? biask : biasv;
    int row0 = blockIdx.x * 64;

    __shared__ _Float16 smem[32768];   // 64 KB: Xs[64][512] granule-swizzled;
                                       // epilogue tile overlays after barrier

    int tid = threadIdx.x;
    int wave = tid >> 6, lane = tid & 63;
    int l32 = lane & 31, hi = lane >> 5, hi8 = hi * 8;
    int wr = wave >> 1, wc = wave & 1;   // wave tile: rows wr*32, cols wc*64

    // ---- stage X tile: 64 rows x 512 cols, fp32 -> fp16, XOR-swizzled ----
    // per instr: 64 lanes read 2048 contiguous bytes of one row (perfect
    // coalescing); LDS granule g^(row&7) spreads the K-major read banks.
    {
        int g = tid & 63;              // granule (8 fp32) within row
        int gcol = g * 8;
        int rbase = tid >> 6;
#pragma unroll 4
        for (int it = 0; it < 16; ++it) {
            int row = it * 4 + rbase;
            const float4* xp =
                (const float4*)(x + (size_t)(row0 + row) * 512 + gcol);
            float4 a0 = xp[0], a1 = xp[1];
            half8_t h;
            h[0] = (_Float16)a0.x; h[1] = (_Float16)a0.y;
            h[2] = (_Float16)a0.z; h[3] = (_Float16)a0.w;
            h[4] = (_Float16)a1.x; h[5] = (_Float16)a1.y;
            h[6] = (_Float16)a1.z; h[7] = (_Float16)a1.w;
            int gs = g ^ (row & 7);
            *(half8_t*)&smem[row * 512 + gs * 8] = h;
        }
    }
    __syncthreads();

    // ---- K-loop: 32 steps x (1 ds_read A + 2 global B + 2 MFMA32) --------
    const _Float16* w0p = Wt + (size_t)(wc * 64 + l32) * 512 + hi8;
    const _Float16* w1p = w0p + 32 * 512;
    const _Float16* abase = &smem[(wr * 32 + l32) * 512];
    int axor = l32 & 7;

#define AF(ks) (*(const half8_t*)&abase[((((ks) * 2 + hi) ^ axor)) * 8])
#define BF0(ks) (*(const half8_t*)(w0p + (ks) * 16))
#define BF1(ks) (*(const half8_t*)(w1p + (ks) * 16))

    f32x16 acc0 = {}, acc1 = {};
    half8_t afa = AF(0), b0a = BF0(0), b1a = BF1(0);
    half8_t afb, b0b, b1b;
    for (int ks = 0; ks < 32; ks += 2) {
        afb = AF(ks + 1); b0b = BF0(ks + 1); b1b = BF1(ks + 1);
        acc0 = MFMA32(afa, b0a, acc0);
        acc1 = MFMA32(afa, b1a, acc1);
        if (ks + 2 < 32) {
            afa = AF(ks + 2); b0a = BF0(ks + 2); b1a = BF1(ks + 2);
        }
        acc0 = MFMA32(afb, b0b, acc0);
        acc1 = MFMA32(afb, b1b, acc1);
    }
#undef AF
#undef BF0
#undef BF1

    // ---- epilogue: bias(+scale), assemble in LDS, coalesced stores -------
    __syncthreads();   // Xs dead; overlay epilogue tile
    float scale = (y == 0) ? SCALE_Q : 1.0f;
    float bc0 = bias[wc * 64 + l32];
    float bc1 = bias[wc * 64 + 32 + l32];

    if (y < 2) {
        // row-major [s][d] tile: [64][136]
#pragma unroll
        for (int r = 0; r < 16; r++) {
            int crow = (r & 3) + 8 * (r >> 2) + 4 * hi;
            smem[(wr * 32 + crow) * 136 + wc * 64 + l32] =
                (_Float16)((acc0[r] + bc0) * scale);
            smem[(wr * 32 + crow) * 136 + wc * 64 + 32 + l32] =
                (_Float16)((acc1[r] + bc1) * scale);
        }
        __syncthreads();
        int srow = tid >> 2, sc = (tid & 3) * 32;
        _Float16* outp =
            ((y == 0) ? qbuf : kbuf) + (size_t)(row0 + srow) * 128 + sc;
        for (int i = 0; i < 4; i++)
            *(half8_t*)(outp + i * 8) =
                *(const half8_t*)&smem[srow * 136 + sc + i * 8];
    } else {
        // transposed [d][s] tile: [128][72]
#pragma unroll
        for (int r = 0; r < 16; r++) {
            int crow = (r & 3) + 8 * (r >> 2) + 4 * hi;
            smem[(wc * 64 + l32) * 72 + wr * 32 + crow] =
                (_Float16)(acc0[r] + bc0);
            smem[(wc * 64 + 32 + l32) * 72 + wr * 32 + crow] =
                (_Float16)(acc1[r] + bc1);
        }
        __syncthreads();
        int d = tid >> 1, off = (tid & 1) * 32;
        int bbn = row0 >> 11, s0 = row0 & 2047;
        _Float16* outp = vtbuf + ((size_t)bbn * 128 + d) * 2048 + s0 + off;
        for (int i = 0; i < 4; i++)
            *(half8_t*)(outp + i * 8) =
                *(const half8_t*)&smem[d * 72 + off + i * 8];
    }
}

// ---------------------------------------------------------------------------
// Kernel 2: flash attention, 32x32 MFMA, in-register P (no Pt LDS).
// 1 block = 64 q rows, 8 waves: {g = kv-half} x {qsub = 32-q-subtile} x
// {kt = 32-key-subtile}. Swapped QK^T (S^T = K Q^T) puts q = lane&31 so the
// softmax max/sum folds with ONE shfl_xor(32); alpha & 1/l are lane-local.
// P -> PV B-operand via 4 shfl_xor(32) cross-hi exchange (T12 mechanism).
// O^T accumulated in regs; 4 partial (O,m,l) chains merged in LDS at end.
// ---------------------------------------------------------------------------
__global__ __launch_bounds__(512, 2) void attn_kernel(
    const _Float16* __restrict__ qbuf, const _Float16* __restrict__ kbuf,
    const _Float16* __restrict__ vtbuf, float* __restrict__ out) {
    int bb = blockIdx.x >> 5;
    int q0 = (blockIdx.x & 31) * 64;
    int tid = threadIdx.x, wave = tid >> 6, lane = tid & 63;
    int g = wave >> 2, qsub = (wave >> 1) & 1, kt = wave & 1;
    int l32 = lane & 31, hi = lane >> 5, hi8 = hi * 8;

    __shared__ _Float16 smem[71680];   // 143,360 B
    _Float16* KsA = smem + g * 35840;            // [64][136]
    _Float16* KsB = KsA + 8704;
    _Float16* VsA = smem + g * 35840 + 17408;    // [128][72]  (V^T: [d][key])
    _Float16* VsB = VsA + 9216;

    // Q fragments: B-frag for 32x32x16: B[k=hi*8+j][q=l32]
    half8_t qf[8];
    {
        const _Float16* qrow =
            qbuf + ((size_t)bb * 2048 + q0 + qsub * 32 + l32) * 128 + hi8;
#pragma unroll
        for (int kc = 0; kc < 8; kc++)
            qf[kc] = *(const half8_t*)(qrow + kc * 16);
    }

    const _Float16* kbase = kbuf + ((size_t)bb * 2048 + g * 1024) * 128;
    const _Float16* vbase = vtbuf + (size_t)bb * 128 * 2048 + g * 1024;

    int tg = tid & 255;                           // thread within kv-group
    int krow = tg >> 2, kcol = (tg & 3) * 32;     // K stage: 64 x 128
    int vrow = tg >> 1, vcol = (tg & 1) * 32;     // V stage: 128 x 64

    // prologue: stage tile 0 into buffer A
    {
        const half8_t* ks = (const half8_t*)(kbase + (size_t)krow * 128 + kcol);
        half8_t k0 = ks[0], k1 = ks[1], k2 = ks[2], k3 = ks[3];
        const half8_t* vs = (const half8_t*)(vbase + (size_t)vrow * 2048 + vcol);
        half8_t v0 = vs[0], v1 = vs[1], v2 = vs[2], v3 = vs[3];
        *(half8_t*)&KsA[krow * 136 + kcol]      = k0;
        *(half8_t*)&KsA[krow * 136 + kcol + 8]  = k1;
        *(half8_t*)&KsA[krow * 136 + kcol + 16] = k2;
        *(half8_t*)&KsA[krow * 136 + kcol + 24] = k3;
        *(half8_t*)&VsA[vrow * 72 + vcol]       = v0;
        *(half8_t*)&VsA[vrow * 72 + vcol + 8]   = v1;
        *(half8_t*)&VsA[vrow * 72 + vcol + 16]  = v2;
        *(half8_t*)&VsA[vrow * 72 + vcol + 24]  = v3;
    }
    __syncthreads();

    f32x16 acc0 = {}, acc1 = {}, acc2 = {}, acc3 = {};
    float m = -INFINITY, l = 0.0f;

    for (int it = 0; it < 16; ++it) {
        bool more = it < 15;
        half8_t nk0, nk1, nk2, nk3, nv0, nv1, nv2, nv3;
        if (more) {   // T14: issue next-tile loads before compute
            const half8_t* ks =
                (const half8_t*)(kbase + (size_t)((it + 1) * 64 + krow) * 128 + kcol);
            nk0 = ks[0]; nk1 = ks[1]; nk2 = ks[2]; nk3 = ks[3];
            const half8_t* vs =
                (const half8_t*)(vbase + (size_t)vrow * 2048 + (it + 1) * 64 + vcol);
            nv0 = vs[0]; nv1 = vs[1]; nv2 = vs[2]; nv3 = vs[3];
        }

        // S^T[key][q] = K Q^T for this wave's 32 keys (kt subtile)
        f32x16 sf = {};
        __builtin_amdgcn_s_setprio(1);
#pragma unroll
        for (int kc = 0; kc < 8; kc++) {
            half8_t kf =
                *(const half8_t*)&KsA[(kt * 32 + l32) * 136 + kc * 16 + hi8];
            sf = MFMA32(kf, qf[kc], sf);
        }
        __builtin_amdgcn_s_setprio(0);

        // online softmax; q = l32 per lane; keys split across hi halves
        float mx = sf[0];
#pragma unroll
        for (int i = 1; i < 16; i++) mx = fmaxf(mx, sf[i]);
        mx = fmaxf(mx, __shfl_xor(mx, 32, 64));
        if (!__all(mx <= m + 8.0f)) {   // T13 defer-max (THR=8)
            float mn = fmaxf(m, mx);
            float al = exp2f(m - mn);
            l *= al;
            acc0 *= al; acc1 *= al; acc2 *= al; acc3 *= al;
            m = mn;
        }
        float p[16];
        float rs = 0.0f;
#pragma unroll
        for (int i = 0; i < 16; i++) {
            p[i] = exp2f(sf[i] - m);
            rs += p[i];
        }
        rs += __shfl_xor(rs, 32, 64);
        l += rs;

        // pack P (key = (r&3)+8*(r>>2)+4*hi), cross-hi exchange -> B-frags
        unsigned int u0 = pkh(p[0], p[1]),   u1 = pkh(p[2], p[3]);
        unsigned int u2 = pkh(p[4], p[5]),   u3 = pkh(p[6], p[7]);
        unsigned int u4 = pkh(p[8], p[9]),   u5 = pkh(p[10], p[11]);
        unsigned int u6 = pkh(p[12], p[13]), u7 = pkh(p[14], p[15]);
        unsigned int x00 = hi ? u0 : u2, x01 = hi ? u1 : u3;
        unsigned int x10 = hi ? u4 : u6, x11 = hi ? u5 : u7;
        unsigned int r00 = __shfl_xor(x00, 32, 64), r01 = __shfl_xor(x01, 32, 64);
        unsigned int r10 = __shfl_xor(x10, 32, 64), r11 = __shfl_xor(x11, 32, 64);
        uint32x4 b0u, b1u;
        b0u[0] = hi ? r00 : u0; b0u[1] = hi ? r01 : u1;
        b0u[2] = hi ? u2 : r00; b0u[3] = hi ? u3 : r01;
        b1u[0] = hi ? r10 : u4; b1u[1] = hi ? r11 : u5;
        b1u[2] = hi ? u6 : r10; b1u[3] = hi ? u7 : r11;
        half8_t pb0 = __builtin_bit_cast(half8_t, b0u);
        half8_t pb1 = __builtin_bit_cast(half8_t, b1u);

        // O^T[d][q] += V^T P^T  (A = V^T rows d, B = P^T cols q)
        __builtin_amdgcn_s_setprio(1);
        {
            half8_t v0 = *(const half8_t*)&VsA[(0 * 32 + l32) * 72 + kt * 32 + hi8];
            acc0 = MFMA32(v0, pb0, acc0);
            half8_t v1 = *(const half8_t*)&VsA[(0 * 32 + l32) * 72 + kt * 32 + 16 + hi8];
            acc0 = MFMA32(v1, pb1, acc0);
            half8_t v2 = *(const half8_t*)&VsA[(1 * 32 + l32) * 72 + kt * 32 + hi8];
            acc1 = MFMA32(v2, pb0, acc1);
            half8_t v3 = *(const half8_t*)&VsA[(1 * 32 + l32) * 72 + kt * 32 + 16 + hi8];
            acc1 = MFMA32(v3, pb1, acc1);
            half8_t v4 = *(const half8_t*)&VsA[(2 * 32 + l32) * 72 + kt * 32 + hi8];
            acc2 = MFMA32(v4, pb0, acc2);
            half8_t v5 = *(const half8_t*)&VsA[(2 * 32 + l32) * 72 + kt * 32 + 16 + hi8];
            acc2 = MFMA32(v5, pb1, acc2);
            half8_t v6 = *(const half8_t*)&VsA[(3 * 32 + l32) * 72 + kt * 32 + hi8];
            acc3 = MFMA32(v6, pb0, acc3);
            half8_t v7 = *(const half8_t*)&VsA[(3 * 32 + l32) * 72 + kt * 32 + 16 + hi8];
            acc3 = MFMA32(v7, pb1, acc3);
        }
        __builtin_amdgcn_s_setprio(0);

        if (more) {
            *(half8_t*)&KsB[krow * 136 + kcol]      = nk0;
            *(half8_t*)&KsB[krow * 136 + kcol + 8]  = nk1;
            *(half8_t*)&KsB[krow * 136 + kcol + 16] = nk2;
            *(half8_t*)&KsB[krow * 136 + kcol + 24] = nk3;
            *(half8_t*)&VsB[vrow * 72 + vcol]       = nv0;
            *(half8_t*)&VsB[vrow * 72 + vcol + 8]   = nv1;
            *(half8_t*)&VsB[vrow * 72 + vcol + 16]  = nv2;
            *(half8_t*)&VsB[vrow * 72 + vcol + 24]  = nv3;
        }
        __syncthreads();
        _Float16* tmp;
        tmp = KsA; KsA = KsB; KsB = tmp;
        tmp = VsA; VsA = VsB; VsB = tmp;
    }

    // -----------------------------------------------------------------------
    // Merge the 4 partial chains (g,kt) per qsub. Tree: kt-pairs, then g-pairs.
    // Scratch overlays dead K/V LDS: R1[4 regions][128][33] f32 + ml[4][64].
    // -----------------------------------------------------------------------
    float* R1 = (float*)smem;
    const int RS = 33;
    int wid2 = g * 2 + qsub;
    float* Om = R1 + wid2 * (128 * RS);
    float* Ml = R1 + 4 * 128 * RS + wid2 * 64;

#define STORE_ACC(DST, A, DT)                                             \
    {                                                                     \
        _Pragma("unroll") for (int r = 0; r < 16; r++) {                  \
            int d = (r & 3) + 8 * (r >> 2) + 4 * hi + 32 * (DT);          \
            (DST)[d * RS + l32] = (A)[r];                                 \
        }                                                                 \
    }
#define MERGE_ACC(SRC, A, DT)                                             \
    {                                                                     \
        _Pragma("unroll") for (int r = 0; r < 16; r++) {                  \
            int d = (r & 3) + 8 * (r >> 2) + 4 * hi + 32 * (DT);          \
            (A)[r] = (A)[r] * sa + (SRC)[d * RS + l32] * sb;              \
        }                                                                 \
    }

    if (kt == 1) {
        STORE_ACC(Om, acc0, 0); STORE_ACC(Om, acc1, 1);
        STORE_ACC(Om, acc2, 2); STORE_ACC(Om, acc3, 3);
        if (hi == 0) { Ml[l32] = m; Ml[32 + l32] = l; }
    }
    __syncthreads();
    if (kt == 0) {
        float m1 = Ml[l32], l1 = Ml[32 + l32];
        float mf = fmaxf(m, m1);
        float sa = exp2f(m - mf), sb = exp2f(m1 - mf);
        l = l * sa + l1 * sb;
        m = mf;
        MERGE_ACC(Om, acc0, 0); MERGE_ACC(Om, acc1, 1);
        MERGE_ACC(Om, acc2, 2); MERGE_ACC(Om, acc3, 3);
    }
    __syncthreads();
    if (kt == 0 && g == 1) {
        float* Om2 = R1 + qsub * (128 * RS);
        float* Ml2 = R1 + 4 * 128 * RS + qsub * 64;
        STORE_ACC(Om2, acc0, 0); STORE_ACC(Om2, acc1, 1);
        STORE_ACC(Om2, acc2, 2); STORE_ACC(Om2, acc3, 3);
        if (hi == 0) { Ml2[l32] = m; Ml2[32 + l32] = l; }
    }
    __syncthreads();
    if (kt == 0 && g == 0) {
        float* Om2 = R1 + qsub * (128 * RS);
        float* Ml2 = R1 + 4 * 128 * RS + qsub * 64;
        float m1 = Ml2[l32], l1 = Ml2[32 + l32];
        float mf = fmaxf(m, m1);
        float sa = exp2f(m - mf), sb = exp2f(m1 - mf);
        float lf = l * sa + l1 * sb;
        float inv = 1.0f / lf;
        float* op = out + ((size_t)bb * 2048 + q0 + qsub * 32 + l32) * 128;
#define FINAL_ACC(A, DT)                                                  \
        {                                                                 \
            _Pragma("unroll") for (int r = 0; r < 16; r++) {              \
                int d = (r & 3) + 8 * (r >> 2) + 4 * hi + 32 * (DT);      \
                op[d] = ((A)[r] * sa + Om2[d * RS + l32] * sb) * inv;     \
            }                                                             \
        }
        FINAL_ACC(acc0, 0); FINAL_ACC(acc1, 1);
        FINAL_ACC(acc2, 2); FINAL_ACC(acc3, 3);
#undef FINAL_ACC
    }
#undef STORE_ACC
#undef MERGE_ACC
}

// ---------------------------------------------------------------------------
extern "C" void kernel_launch(void* const* d_in, const int* in_sizes, int n_in,
                              void* d_out, int out_size, void* d_ws,
                              size_t ws_size, hipStream_t stream) {
    const float* q_in = (const float*)d_in[0];
    const float* k_in = (const float*)d_in[1];
    const float* v_in = (const float*)d_in[2];
    const float* Wq = (const float*)d_in[3];
    const float* Wk = (const float*)d_in[4];
    const float* Wv = (const float*)d_in[5];
    const float* bq = (const float*)d_in[6];
    const float* bk = (const float*)d_in[7];
    const float* bv = (const float*)d_in[8];
    float* out = (float*)d_out;

    char* ws = (char*)d_ws;
    _Float16* WtAll = (_Float16*)ws;                    // 3 * 65536 * 2 B
    _Float16* qbuf  = (_Float16*)(ws + 393216);         // 16384*128*2 = 4 MB
    _Float16* kbuf  = (_Float16*)(ws + 4587520);        // 4 MB
    _Float16* vtbuf = (_Float16*)(ws + 8781824);        // 4 MB (transposed)

    wt_kernel<<<dim3(256, 3), 256, 0, stream>>>(Wq, Wk, Wv, WtAll);
    proj_kernel<<<dim3(256, 3), 256, 0, stream>>>(q_in, k_in, v_in, WtAll, bq,
                                                  bk, bv, qbuf, kbuf, vtbuf);
    attn_kernel<<<dim3(256), 512, 0, stream>>>(qbuf, kbuf, vtbuf, out);
}

// Round 6
// 181.157 us; speedup vs baseline: 1.1156x; 1.1156x over previous
//
#include <hip/hip_runtime.h>
#include <math.h>

typedef _Float16 half8_t __attribute__((ext_vector_type(8)));
typedef _Float16 half4_t __attribute__((ext_vector_type(4)));
typedef _Float16 half2_t __attribute__((ext_vector_type(2)));
typedef float f32x4 __attribute__((ext_vector_type(4)));
typedef float f32x16 __attribute__((ext_vector_type(16)));
typedef unsigned int uint32x4 __attribute__((ext_vector_type(4)));

#define MFMA16(a, b, c) __builtin_amdgcn_mfma_f32_16x16x32_f16((a), (b), (c), 0, 0, 0)
#define MFMA32(a, b, c) __builtin_amdgcn_mfma_f32_32x32x16_f16((a), (b), (c), 0, 0, 0)

// log2(e) / sqrt(128): fold softmax scale AND exp->exp2 conversion into q.
#define SCALE_Q (0.08838834764831845f * 1.44269504088896340736f)

static __device__ inline unsigned int pkh(float a, float b) {
    half2_t h;
    h[0] = (_Float16)a;
    h[1] = (_Float16)b;
    return __builtin_bit_cast(unsigned int, h);
}

// ---------------------------------------------------------------------------
// Kernel 0: W [512][128] fp32  ->  Wt [128][512] fp16   (x3 for q,k,v)
// ---------------------------------------------------------------------------
__global__ __launch_bounds__(256) void wt_kernel(const float* __restrict__ Wq,
                                                 const float* __restrict__ Wk,
                                                 const float* __restrict__ Wv,
                                                 _Float16* __restrict__ WtAll) {
    int y = blockIdx.y;
    const float* W = (y == 0) ? Wq : (y == 1) ? Wk : Wv;
    int idx = blockIdx.x * 256 + threadIdx.x;
    int kk = idx >> 7;
    int d  = idx & 127;
    WtAll[y * 65536 + d * 512 + kk] = (_Float16)W[idx];
}

// ---------------------------------------------------------------------------
// Kernel 1: projection GEMM v3.  C[16384][128] = X[16384][512] @ W + b
// v1's proven 2-phase structure (reg prefetch, dbuf LDS, ONE barrier/K-step)
// with 64-row tiles: grid (256,3) = 768 blocks -> ~3 blocks/CU co-resident,
// so other blocks' waves hide each block's load->ds_write stall.
// LDS 30.7 KB. (Round-5's per-wave global W gather reverted: W staged in LDS.)
// ---------------------------------------------------------------------------
__global__ __launch_bounds__(256) void proj_kernel(
    const float* __restrict__ q_in, const float* __restrict__ k_in,
    const float* __restrict__ v_in, const _Float16* __restrict__ WtAll,
    const float* __restrict__ biasq, const float* __restrict__ biask,
    const float* __restrict__ biasv,
    _Float16* __restrict__ qbuf, _Float16* __restrict__ kbuf,
    _Float16* __restrict__ vtbuf) {
    int y = blockIdx.y;
    const float* x = (y == 0) ? q_in : (y == 1) ? k_in : v_in;
    const _Float16* Wt = WtAll + y * 65536;
    const float* bias = (y == 0) ? biasq : (y == 1) ? biask : biasv;
    int row0 = blockIdx.x * 64;

    __shared__ _Float16 smem[15360];   // 30,720 B; epilogue overlays staging
    _Float16* AsA = smem;              // [64][40]   (BK=32 +8 pad)
    _Float16* WsA = smem + 2560;       // [128][40]  (W^T tile: [d_att][k])
    _Float16* AsB = smem + 7680;
    _Float16* WsB = smem + 10240;

    int tid = threadIdx.x;
    int wave = tid >> 6, lane = tid & 63, quad = lane >> 4, l16 = lane & 15;
    int wm = (wave & 1) * 32, wn = (wave >> 1) * 64;
    int arow = tid >> 2, acol = (tid & 3) * 8;    // A stage: 64 rows x 32 k
    int wrow = tid >> 1, wcol = (tid & 1) * 16;   // W stage: 128 d x 32 k

    f32x4 acc[2][4] = {};

    // prologue: stage K-block 0 into buffer A
    {
        const float4* ap = (const float4*)(x + (size_t)(row0 + arow) * 512 + acol);
        float4 a0 = ap[0], a1 = ap[1];
        const half8_t* wp = (const half8_t*)(Wt + wrow * 512 + wcol);
        half8_t w0 = wp[0], w1 = wp[1];
        half8_t h;
        h[0] = (_Float16)a0.x; h[1] = (_Float16)a0.y;
        h[2] = (_Float16)a0.z; h[3] = (_Float16)a0.w;
        h[4] = (_Float16)a1.x; h[5] = (_Float16)a1.y;
        h[6] = (_Float16)a1.z; h[7] = (_Float16)a1.w;
        *(half8_t*)&AsA[arow * 40 + acol]     = h;
        *(half8_t*)&WsA[wrow * 40 + wcol]     = w0;
        *(half8_t*)&WsA[wrow * 40 + wcol + 8] = w1;
    }
    __syncthreads();

    for (int kb = 0; kb < 512; kb += 32) {
        bool more = (kb + 32) < 512;
        float4 a0, a1;
        half8_t w0, w1;
        if (more) {   // T14: issue next-tile loads BEFORE compute
            const float4* ap =
                (const float4*)(x + (size_t)(row0 + arow) * 512 + kb + 32 + acol);
            a0 = ap[0]; a1 = ap[1];
            const half8_t* wp = (const half8_t*)(Wt + wrow * 512 + kb + 32 + wcol);
            w0 = wp[0]; w1 = wp[1];
        }

        half8_t af[2], bf[4];
        for (int mt = 0; mt < 2; mt++)
            af[mt] = *(const half8_t*)&AsA[(wm + mt * 16 + l16) * 40 + quad * 8];
        for (int nt = 0; nt < 4; nt++)
            bf[nt] = *(const half8_t*)&WsA[(wn + nt * 16 + l16) * 40 + quad * 8];
        for (int mt = 0; mt < 2; mt++)
            for (int nt = 0; nt < 4; nt++)
                acc[mt][nt] = MFMA16(af[mt], bf[nt], acc[mt][nt]);

        if (more) {   // convert + write into the other buffer
            half8_t h;
            h[0] = (_Float16)a0.x; h[1] = (_Float16)a0.y;
            h[2] = (_Float16)a0.z; h[3] = (_Float16)a0.w;
            h[4] = (_Float16)a1.x; h[5] = (_Float16)a1.y;
            h[6] = (_Float16)a1.z; h[7] = (_Float16)a1.w;
            *(half8_t*)&AsB[arow * 40 + acol]     = h;
            *(half8_t*)&WsB[wrow * 40 + wcol]     = w0;
            *(half8_t*)&WsB[wrow * 40 + wcol + 8] = w1;
        }
        __syncthreads();
        _Float16* tp;
        tp = AsA; AsA = AsB; AsB = tp;
        tp = WsA; WsA = WsB; WsB = tp;
    }

    // Epilogue: bias + scale, assemble tile in LDS, coalesced store.
    float scale = (y == 0) ? SCALE_Q : 1.0f;
    if (y < 2) {
        // row-major [s][d] tile in smem[64][136]
        for (int mt = 0; mt < 2; mt++)
            for (int nt = 0; nt < 4; nt++) {
                int d = wn + nt * 16 + l16;
                float b = bias[d];
                for (int r = 0; r < 4; r++)
                    smem[(wm + mt * 16 + quad * 4 + r) * 136 + d] =
                        (_Float16)((acc[mt][nt][r] + b) * scale);
            }
        __syncthreads();
        int srow = tid >> 2, sc = (tid & 3) * 32;
        _Float16* outp =
            ((y == 0) ? qbuf : kbuf) + (size_t)(row0 + srow) * 128 + sc;
        for (int i = 0; i < 4; i++)
            *(half8_t*)(outp + i * 8) =
                *(const half8_t*)&smem[srow * 136 + sc + i * 8];
    } else {
        // transposed [d][s] tile in smem[128][72]
        for (int mt = 0; mt < 2; mt++)
            for (int nt = 0; nt < 4; nt++) {
                int d = wn + nt * 16 + l16;
                float b = bias[d];
                half4_t pk;
                for (int r = 0; r < 4; r++)
                    pk[r] = (_Float16)(acc[mt][nt][r] + b);
                *(half4_t*)&smem[d * 72 + wm + mt * 16 + quad * 4] = pk;
            }
        __syncthreads();
        int d = tid >> 1, off = (tid & 1) * 32;
        int bbn = row0 >> 11, s0 = row0 & 2047;
        _Float16* outp = vtbuf + ((size_t)bbn * 128 + d) * 2048 + s0 + off;
        for (int i = 0; i < 4; i++)
            *(half8_t*)(outp + i * 8) =
                *(const half8_t*)&smem[d * 72 + off + i * 8];
    }
}

// ---------------------------------------------------------------------------
// Kernel 2: flash attention, 32x32 MFMA, in-register P (no Pt LDS).
// 1 block = 64 q rows, 8 waves: {g = kv-half} x {qsub = 32-q-subtile} x
// {kt = 32-key-subtile}. Swapped QK^T (S^T = K Q^T) puts q = lane&31 so the
// softmax max/sum folds with ONE shfl_xor(32); alpha & 1/l are lane-local.
// P -> PV B-operand via 4 shfl_xor(32) cross-hi exchange (T12 mechanism).
// O^T accumulated in regs; 4 partial (O,m,l) chains merged in LDS at end.
// ---------------------------------------------------------------------------
__global__ __launch_bounds__(512, 2) void attn_kernel(
    const _Float16* __restrict__ qbuf, const _Float16* __restrict__ kbuf,
    const _Float16* __restrict__ vtbuf, float* __restrict__ out) {
    int bb = blockIdx.x >> 5;
    int q0 = (blockIdx.x & 31) * 64;
    int tid = threadIdx.x, wave = tid >> 6, lane = tid & 63;
    int g = wave >> 2, qsub = (wave >> 1) & 1, kt = wave & 1;
    int l32 = lane & 31, hi = lane >> 5, hi8 = hi * 8;

    __shared__ _Float16 smem[71680];   // 143,360 B
    _Float16* KsA = smem + g * 35840;            // [64][136]
    _Float16* KsB = KsA + 8704;
    _Float16* VsA = smem + g * 35840 + 17408;    // [128][72]  (V^T: [d][key])
    _Float16* VsB = VsA + 9216;

    // Q fragments: B-frag for 32x32x16: B[k=hi*8+j][q=l32]
    half8_t qf[8];
    {
        const _Float16* qrow =
            qbuf + ((size_t)bb * 2048 + q0 + qsub * 32 + l32) * 128 + hi8;
#pragma unroll
        for (int kc = 0; kc < 8; kc++)
            qf[kc] = *(const half8_t*)(qrow + kc * 16);
    }

    const _Float16* kbase = kbuf + ((size_t)bb * 2048 + g * 1024) * 128;
    const _Float16* vbase = vtbuf + (size_t)bb * 128 * 2048 + g * 1024;

    int tg = tid & 255;                           // thread within kv-group
    int krow = tg >> 2, kcol = (tg & 3) * 32;     // K stage: 64 x 128
    int vrow = tg >> 1, vcol = (tg & 1) * 32;     // V stage: 128 x 64

    // prologue: stage tile 0 into buffer A
    {
        const half8_t* ks = (const half8_t*)(kbase + (size_t)krow * 128 + kcol);
        half8_t k0 = ks[0], k1 = ks[1], k2 = ks[2], k3 = ks[3];
        const half8_t* vs = (const half8_t*)(vbase + (size_t)vrow * 2048 + vcol);
        half8_t v0 = vs[0], v1 = vs[1], v2 = vs[2], v3 = vs[3];
        *(half8_t*)&KsA[krow * 136 + kcol]      = k0;
        *(half8_t*)&KsA[krow * 136 + kcol + 8]  = k1;
        *(half8_t*)&KsA[krow * 136 + kcol + 16] = k2;
        *(half8_t*)&KsA[krow * 136 + kcol + 24] = k3;
        *(half8_t*)&VsA[vrow * 72 + vcol]       = v0;
        *(half8_t*)&VsA[vrow * 72 + vcol + 8]   = v1;
        *(half8_t*)&VsA[vrow * 72 + vcol + 16]  = v2;
        *(half8_t*)&VsA[vrow * 72 + vcol + 24]  = v3;
    }
    __syncthreads();

    f32x16 acc0 = {}, acc1 = {}, acc2 = {}, acc3 = {};
    float m = -INFINITY, l = 0.0f;

    for (int it = 0; it < 16; ++it) {
        bool more = it < 15;
        half8_t nk0, nk1, nk2, nk3, nv0, nv1, nv2, nv3;
        if (more) {   // T14: issue next-tile loads before compute
            const half8_t* ks =
                (const half8_t*)(kbase + (size_t)((it + 1) * 64 + krow) * 128 + kcol);
            nk0 = ks[0]; nk1 = ks[1]; nk2 = ks[2]; nk3 = ks[3];
            const half8_t* vs =
                (const half8_t*)(vbase + (size_t)vrow * 2048 + (it + 1) * 64 + vcol);
            nv0 = vs[0]; nv1 = vs[1]; nv2 = vs[2]; nv3 = vs[3];
        }

        // S^T[key][q] = K Q^T for this wave's 32 keys (kt subtile)
        f32x16 sf = {};
        __builtin_amdgcn_s_setprio(1);
#pragma unroll
        for (int kc = 0; kc < 8; kc++) {
            half8_t kf =
                *(const half8_t*)&KsA[(kt * 32 + l32) * 136 + kc * 16 + hi8];
            sf = MFMA32(kf, qf[kc], sf);
        }
        __builtin_amdgcn_s_setprio(0);

        // online softmax; q = l32 per lane; keys split across hi halves
        float mx = sf[0];
#pragma unroll
        for (int i = 1; i < 16; i++) mx = fmaxf(mx, sf[i]);
        mx = fmaxf(mx, __shfl_xor(mx, 32, 64));
        if (!__all(mx <= m + 8.0f)) {   // T13 defer-max (THR=8)
            float mn = fmaxf(m, mx);
            float al = exp2f(m - mn);
            l *= al;
            acc0 *= al; acc1 *= al; acc2 *= al; acc3 *= al;
            m = mn;
        }
        float p[16];
        float rs = 0.0f;
#pragma unroll
        for (int i = 0; i < 16; i++) {
            p[i] = exp2f(sf[i] - m);
            rs += p[i];
        }
        rs += __shfl_xor(rs, 32, 64);
        l += rs;

        // pack P (key = (r&3)+8*(r>>2)+4*hi), cross-hi exchange -> B-frags
        unsigned int u0 = pkh(p[0], p[1]),   u1 = pkh(p[2], p[3]);
        unsigned int u2 = pkh(p[4], p[5]),   u3 = pkh(p[6], p[7]);
        unsigned int u4 = pkh(p[8], p[9]),   u5 = pkh(p[10], p[11]);
        unsigned int u6 = pkh(p[12], p[13]), u7 = pkh(p[14], p[15]);
        unsigned int x00 = hi ? u0 : u2, x01 = hi ? u1 : u3;
        unsigned int x10 = hi ? u4 : u6, x11 = hi ? u5 : u7;
        unsigned int r00 = __shfl_xor(x00, 32, 64), r01 = __shfl_xor(x01, 32, 64);
        unsigned int r10 = __shfl_xor(x10, 32, 64), r11 = __shfl_xor(x11, 32, 64);
        uint32x4 b0u, b1u;
        b0u[0] = hi ? r00 : u0; b0u[1] = hi ? r01 : u1;
        b0u[2] = hi ? u2 : r00; b0u[3] = hi ? u3 : r01;
        b1u[0] = hi ? r10 : u4; b1u[1] = hi ? r11 : u5;
        b1u[2] = hi ? u6 : r10; b1u[3] = hi ? u7 : r11;
        half8_t pb0 = __builtin_bit_cast(half8_t, b0u);
        half8_t pb1 = __builtin_bit_cast(half8_t, b1u);

        // O^T[d][q] += V^T P^T  (A = V^T rows d, B = P^T cols q)
        __builtin_amdgcn_s_setprio(1);
        {
            half8_t v0 = *(const half8_t*)&VsA[(0 * 32 + l32) * 72 + kt * 32 + hi8];
            acc0 = MFMA32(v0, pb0, acc0);
            half8_t v1 = *(const half8_t*)&VsA[(0 * 32 + l32) * 72 + kt * 32 + 16 + hi8];
            acc0 = MFMA32(v1, pb1, acc0);
            half8_t v2 = *(const half8_t*)&VsA[(1 * 32 + l32) * 72 + kt * 32 + hi8];
            acc1 = MFMA32(v2, pb0, acc1);
            half8_t v3 = *(const half8_t*)&VsA[(1 * 32 + l32) * 72 + kt * 32 + 16 + hi8];
            acc1 = MFMA32(v3, pb1, acc1);
            half8_t v4 = *(const half8_t*)&VsA[(2 * 32 + l32) * 72 + kt * 32 + hi8];
            acc2 = MFMA32(v4, pb0, acc2);
            half8_t v5 = *(const half8_t*)&VsA[(2 * 32 + l32) * 72 + kt * 32 + 16 + hi8];
            acc2 = MFMA32(v5, pb1, acc2);
            half8_t v6 = *(const half8_t*)&VsA[(3 * 32 + l32) * 72 + kt * 32 + hi8];
            acc3 = MFMA32(v6, pb0, acc3);
            half8_t v7 = *(const half8_t*)&VsA[(3 * 32 + l32) * 72 + kt * 32 + 16 + hi8];
            acc3 = MFMA32(v7, pb1, acc3);
        }
        __builtin_amdgcn_s_setprio(0);

        if (more) {
            *(half8_t*)&KsB[krow * 136 + kcol]      = nk0;
            *(half8_t*)&KsB[krow * 136 + kcol + 8]  = nk1;
            *(half8_t*)&KsB[krow * 136 + kcol + 16] = nk2;
            *(half8_t*)&KsB[krow * 136 + kcol + 24] = nk3;
            *(half8_t*)&VsB[vrow * 72 + vcol]       = nv0;
            *(half8_t*)&VsB[vrow * 72 + vcol + 8]   = nv1;
            *(half8_t*)&VsB[vrow * 72 + vcol + 16]  = nv2;
            *(half8_t*)&VsB[vrow * 72 + vcol + 24]  = nv3;
        }
        __syncthreads();
        _Float16* tmp;
        tmp = KsA; KsA = KsB; KsB = tmp;
        tmp = VsA; VsA = VsB; VsB = tmp;
    }

    // -----------------------------------------------------------------------
    // Merge the 4 partial chains (g,kt) per qsub. Tree: kt-pairs, then g-pairs.
    // Scratch overlays dead K/V LDS: R1[4 regions][128][33] f32 + ml[4][64].
    // -----------------------------------------------------------------------
    float* R1 = (float*)smem;
    const int RS = 33;
    int wid2 = g * 2 + qsub;
    float* Om = R1 + wid2 * (128 * RS);
    float* Ml = R1 + 4 * 128 * RS + wid2 * 64;

#define STORE_ACC(DST, A, DT)                                             \
    {                                                                     \
        _Pragma("unroll") for (int r = 0; r < 16; r++) {                  \
            int d = (r & 3) + 8 * (r >> 2) + 4 * hi + 32 * (DT);          \
            (DST)[d * RS + l32] = (A)[r];                                 \
        }                                                                 \
    }
#define MERGE_ACC(SRC, A, DT)                                             \
    {                                                                     \
        _Pragma("unroll") for (int r = 0; r < 16; r++) {                  \
            int d = (r & 3) + 8 * (r >> 2) + 4 * hi + 32 * (DT);          \
            (A)[r] = (A)[r] * sa + (SRC)[d * RS + l32] * sb;              \
        }                                                                 \
    }

    if (kt == 1) {
        STORE_ACC(Om, acc0, 0); STORE_ACC(Om, acc1, 1);
        STORE_ACC(Om, acc2, 2); STORE_ACC(Om, acc3, 3);
        if (hi == 0) { Ml[l32] = m; Ml[32 + l32] = l; }
    }
    __syncthreads();
    if (kt == 0) {
        float m1 = Ml[l32], l1 = Ml[32 + l32];
        float mf = fmaxf(m, m1);
        float sa = exp2f(m - mf), sb = exp2f(m1 - mf);
        l = l * sa + l1 * sb;
        m = mf;
        MERGE_ACC(Om, acc0, 0); MERGE_ACC(Om, acc1, 1);
        MERGE_ACC(Om, acc2, 2); MERGE_ACC(Om, acc3, 3);
    }
    __syncthreads();
    if (kt == 0 && g == 1) {
        float* Om2 = R1 + qsub * (128 * RS);
        float* Ml2 = R1 + 4 * 128 * RS + qsub * 64;
        STORE_ACC(Om2, acc0, 0); STORE_ACC(Om2, acc1, 1);
        STORE_ACC(Om2, acc2, 2); STORE_ACC(Om2, acc3, 3);
        if (hi == 0) { Ml2[l32] = m; Ml2[32 + l32] = l; }
    }
    __syncthreads();
    if (kt == 0 && g == 0) {
        float* Om2 = R1 + qsub * (128 * RS);
        float* Ml2 = R1 + 4 * 128 * RS + qsub * 64;
        float m1 = Ml2[l32], l1 = Ml2[32 + l32];
        float mf = fmaxf(m, m1);
        float sa = exp2f(m - mf), sb = exp2f(m1 - mf);
        float lf = l * sa + l1 * sb;
        float inv = 1.0f / lf;
        float* op = out + ((size_t)bb * 2048 + q0 + qsub * 32 + l32) * 128;
#define FINAL_ACC(A, DT)                                                  \
        {                                                                 \
            _Pragma("unroll") for (int r = 0; r < 16; r++) {              \
                int d = (r & 3) + 8 * (r >> 2) + 4 * hi + 32 * (DT);      \
                op[d] = ((A)[r] * sa + Om2[d * RS + l32] * sb) * inv;     \
            }                                                             \
        }
        FINAL_ACC(acc0, 0); FINAL_ACC(acc1, 1);
        FINAL_ACC(acc2, 2); FINAL_ACC(acc3, 3);
#undef FINAL_ACC
    }
#undef STORE_ACC
#undef MERGE_ACC
}

// ---------------------------------------------------------------------------
extern "C" void kernel_launch(void* const* d_in, const int* in_sizes, int n_in,
                              void* d_out, int out_size, void* d_ws,
                              size_t ws_size, hipStream_t stream) {
    const float* q_in = (const float*)d_in[0];
    const float* k_in = (const float*)d_in[1];
    const float* v_in = (const float*)d_in[2];
    const float* Wq = (const float*)d_in[3];
    const float* Wk = (const float*)d_in[4];
    const float* Wv = (const float*)d_in[5];
    const float* bq = (const float*)d_in[6];
    const float* bk = (const float*)d_in[7];
    const float* bv = (const float*)d_in[8];
    float* out = (float*)d_out;

    char* ws = (char*)d_ws;
    _Float16* WtAll = (_Float16*)ws;                    // 3 * 65536 * 2 B
    _Float16* qbuf  = (_Float16*)(ws + 393216);         // 16384*128*2 = 4 MB
    _Float16* kbuf  = (_Float16*)(ws + 4587520);        // 4 MB
    _Float16* vtbuf = (_Float16*)(ws + 8781824);        // 4 MB (transposed)

    wt_kernel<<<dim3(256, 3), 256, 0, stream>>>(Wq, Wk, Wv, WtAll);
    proj_kernel<<<dim3(256, 3), 256, 0, stream>>>(q_in, k_in, v_in, WtAll, bq,
                                                  bk, bv, qbuf, kbuf, vtbuf);
    attn_kernel<<<dim3(256), 512, 0, stream>>>(qbuf, kbuf, vtbuf, out);
}

// Round 7
// 179.513 us; speedup vs baseline: 1.1258x; 1.0092x over previous
//
#include <hip/hip_runtime.h>
#include <math.h>

typedef _Float16 half8_t __attribute__((ext_vector_type(8)));
typedef _Float16 half4_t __attribute__((ext_vector_type(4)));
typedef _Float16 half2_t __attribute__((ext_vector_type(2)));
typedef float f32x4 __attribute__((ext_vector_type(4)));
typedef float f32x16 __attribute__((ext_vector_type(16)));
typedef unsigned int uint32x4 __attribute__((ext_vector_type(4)));

#define MFMA16(a, b, c) __builtin_amdgcn_mfma_f32_16x16x32_f16((a), (b), (c), 0, 0, 0)
#define MFMA32(a, b, c) __builtin_amdgcn_mfma_f32_32x32x16_f16((a), (b), (c), 0, 0, 0)

// log2(e) / sqrt(128): fold softmax scale AND exp->exp2 conversion into q.
#define SCALE_Q (0.08838834764831845f * 1.44269504088896340736f)

static __device__ inline unsigned int pkh(float a, float b) {
    half2_t h;
    h[0] = (_Float16)a;
    h[1] = (_Float16)b;
    return __builtin_bit_cast(unsigned int, h);
}

// ---------------------------------------------------------------------------
// Kernel 0: W [512][128] fp32  ->  Wt [128][512] fp16   (x3 for q,k,v)
// ---------------------------------------------------------------------------
__global__ __launch_bounds__(256) void wt_kernel(const float* __restrict__ Wq,
                                                 const float* __restrict__ Wk,
                                                 const float* __restrict__ Wv,
                                                 _Float16* __restrict__ WtAll) {
    int y = blockIdx.y;
    const float* W = (y == 0) ? Wq : (y == 1) ? Wk : Wv;
    int idx = blockIdx.x * 256 + threadIdx.x;
    int kk = idx >> 7;
    int d  = idx & 127;
    WtAll[y * 65536 + d * 512 + kk] = (_Float16)W[idx];
}

// ---------------------------------------------------------------------------
// Kernel 1: projection GEMM v4.  C[16384][128] = X[16384][512] @ W + b
// v3 structure + DEPTH-2 register prefetch: loads for tile k+2 issued at
// step k; ds_write at step k consumes tile k+1's loads (issued step k-1) so
// issue-to-use spans TWO steps and the compiler emits vmcnt(4), never a full
// drain (T4 counted-vmcnt mechanism via named even/odd regsets, rule #20).
// LDS 30.7 KB, 1 barrier/step, 64-row tiles, grid (256,3).
// ---------------------------------------------------------------------------
__global__ __launch_bounds__(256) void proj_kernel(
    const float* __restrict__ q_in, const float* __restrict__ k_in,
    const float* __restrict__ v_in, const _Float16* __restrict__ WtAll,
    const float* __restrict__ biasq, const float* __restrict__ biask,
    const float* __restrict__ biasv,
    _Float16* __restrict__ qbuf, _Float16* __restrict__ kbuf,
    _Float16* __restrict__ vtbuf) {
    int y = blockIdx.y;
    const float* x = (y == 0) ? q_in : (y == 1) ? k_in : v_in;
    const _Float16* Wt = WtAll + y * 65536;
    const float* bias = (y == 0) ? biasq : (y == 1) ? biask : biasv;
    int row0 = blockIdx.x * 64;

    __shared__ _Float16 smem[15360];   // 30,720 B; epilogue overlays staging
    _Float16* AsA = smem;              // [64][40]   (BK=32 +8 pad) even tiles
    _Float16* WsA = smem + 2560;       // [128][40]
    _Float16* AsB = smem + 7680;       // odd tiles
    _Float16* WsB = smem + 10240;

    int tid = threadIdx.x;
    int wave = tid >> 6, lane = tid & 63, quad = lane >> 4, l16 = lane & 15;
    int wm = (wave & 1) * 32, wn = (wave >> 1) * 64;
    int arow = tid >> 2, acol = (tid & 3) * 8;    // A stage: 64 rows x 32 k
    int wrow = tid >> 1, wcol = (tid & 1) * 16;   // W stage: 128 d x 32 k

    f32x4 acc[2][4] = {};

#define LOADSET(KB, A0, A1, W0, W1)                                          \
    {                                                                        \
        const float4* ap =                                                   \
            (const float4*)(x + (size_t)(row0 + arow) * 512 + (KB) + acol);  \
        A0 = ap[0]; A1 = ap[1];                                              \
        const half8_t* wp =                                                  \
            (const half8_t*)(Wt + wrow * 512 + (KB) + wcol);                 \
        W0 = wp[0]; W1 = wp[1];                                              \
    }
#define STORESET(AS, WS, A0, A1, W0, W1)                                     \
    {                                                                        \
        half8_t h;                                                           \
        h[0] = (_Float16)A0.x; h[1] = (_Float16)A0.y;                        \
        h[2] = (_Float16)A0.z; h[3] = (_Float16)A0.w;                        \
        h[4] = (_Float16)A1.x; h[5] = (_Float16)A1.y;                        \
        h[6] = (_Float16)A1.z; h[7] = (_Float16)A1.w;                        \
        *(half8_t*)&(AS)[arow * 40 + acol]     = h;                          \
        *(half8_t*)&(WS)[wrow * 40 + wcol]     = W0;                         \
        *(half8_t*)&(WS)[wrow * 40 + wcol + 8] = W1;                         \
    }
#define COMPUTE(AS, WS)                                                      \
    {                                                                        \
        half8_t af[2], bf[4];                                                \
        for (int mt = 0; mt < 2; mt++)                                       \
            af[mt] =                                                         \
                *(const half8_t*)&(AS)[(wm + mt * 16 + l16) * 40 + quad * 8];\
        for (int nt = 0; nt < 4; nt++)                                       \
            bf[nt] =                                                         \
                *(const half8_t*)&(WS)[(wn + nt * 16 + l16) * 40 + quad * 8];\
        for (int mt = 0; mt < 2; mt++)                                       \
            for (int nt = 0; nt < 4; nt++)                                   \
                acc[mt][nt] = MFMA16(af[mt], bf[nt], acc[mt][nt]);           \
    }

    float4 ea0, ea1; half8_t ew0, ew1;   // even regset (tiles 0,64,128,...)
    float4 oa0, oa1; half8_t ow0, ow1;   // odd regset  (tiles 32,96,...)

    // prologue: tiles 0 and 32 in flight; write tile 0 (vmcnt(4): odd set
    // still outstanding)
    LOADSET(0, ea0, ea1, ew0, ew1);
    LOADSET(32, oa0, oa1, ow0, ow1);
    STORESET(AsA, WsA, ea0, ea1, ew0, ew1);
    __syncthreads();

    for (int kb = 0; kb < 512; kb += 64) {
        // even step: compute tile kb from bufA
        if (kb + 64 < 512) LOADSET(kb + 64, ea0, ea1, ew0, ew1);
        COMPUTE(AsA, WsA);
        STORESET(AsB, WsB, oa0, oa1, ow0, ow1);   // tile kb+32; vmcnt(4)
        __syncthreads();
        // odd step: compute tile kb+32 from bufB
        if (kb + 96 < 512) LOADSET(kb + 96, oa0, oa1, ow0, ow1);
        COMPUTE(AsB, WsB);
        if (kb + 64 < 512) {
            STORESET(AsA, WsA, ea0, ea1, ew0, ew1);   // tile kb+64; vmcnt(4)
        }
        __syncthreads();
    }
#undef LOADSET
#undef STORESET
#undef COMPUTE

    // Epilogue: bias + scale, assemble tile in LDS, coalesced store.
    float scale = (y == 0) ? SCALE_Q : 1.0f;
    if (y < 2) {
        // row-major [s][d] tile in smem[64][136]
        for (int mt = 0; mt < 2; mt++)
            for (int nt = 0; nt < 4; nt++) {
                int d = wn + nt * 16 + l16;
                float b = bias[d];
                for (int r = 0; r < 4; r++)
                    smem[(wm + mt * 16 + quad * 4 + r) * 136 + d] =
                        (_Float16)((acc[mt][nt][r] + b) * scale);
            }
        __syncthreads();
        int srow = tid >> 2, sc = (tid & 3) * 32;
        _Float16* outp =
            ((y == 0) ? qbuf : kbuf) + (size_t)(row0 + srow) * 128 + sc;
        for (int i = 0; i < 4; i++)
            *(half8_t*)(outp + i * 8) =
                *(const half8_t*)&smem[srow * 136 + sc + i * 8];
    } else {
        // transposed [d][s] tile in smem[128][72]
        for (int mt = 0; mt < 2; mt++)
            for (int nt = 0; nt < 4; nt++) {
                int d = wn + nt * 16 + l16;
                float b = bias[d];
                half4_t pk;
                for (int r = 0; r < 4; r++)
                    pk[r] = (_Float16)(acc[mt][nt][r] + b);
                *(half4_t*)&smem[d * 72 + wm + mt * 16 + quad * 4] = pk;
            }
        __syncthreads();
        int d = tid >> 1, off = (tid & 1) * 32;
        int bbn = row0 >> 11, s0 = row0 & 2047;
        _Float16* outp = vtbuf + ((size_t)bbn * 128 + d) * 2048 + s0 + off;
        for (int i = 0; i < 4; i++)
            *(half8_t*)(outp + i * 8) =
                *(const half8_t*)&smem[d * 72 + off + i * 8];
    }
}

// ---------------------------------------------------------------------------
// Kernel 2: flash attention, 32x32 MFMA, in-register P (no Pt LDS).
// XCD-aware mapping (T1): bb = blockIdx.x & 7 — all 32 q-blocks of batch bb
// land on XCD bb (dispatch round-robins consecutive IDs across the 8 XCDs),
// so the 32x-re-read K/V (1 MB/batch) stays in that XCD's private 4 MB L2.
// 1 block = 64 q rows, 8 waves: {g = kv-half} x {qsub} x {kt}. Swapped QK^T
// (S^T = K Q^T) puts q = lane&31; softmax folds with ONE shfl_xor(32);
// P -> PV B-operand via cross-hi exchange (T12). O^T in regs; 4 partial
// (O,m,l) chains merged in LDS at end.
// ---------------------------------------------------------------------------
__global__ __launch_bounds__(512, 2) void attn_kernel(
    const _Float16* __restrict__ qbuf, const _Float16* __restrict__ kbuf,
    const _Float16* __restrict__ vtbuf, float* __restrict__ out) {
    int bb = blockIdx.x & 7;            // XCD-aligned batch mapping (T1)
    int q0 = (blockIdx.x >> 3) * 64;
    int tid = threadIdx.x, wave = tid >> 6, lane = tid & 63;
    int g = wave >> 2, qsub = (wave >> 1) & 1, kt = wave & 1;
    int l32 = lane & 31, hi = lane >> 5, hi8 = hi * 8;

    __shared__ _Float16 smem[71680];   // 143,360 B
    _Float16* KsA = smem + g * 35840;            // [64][136]
    _Float16* KsB = KsA + 8704;
    _Float16* VsA = smem + g * 35840 + 17408;    // [128][72]  (V^T: [d][key])
    _Float16* VsB = VsA + 9216;

    // Q fragments: B-frag for 32x32x16: B[k=hi*8+j][q=l32]
    half8_t qf[8];
    {
        const _Float16* qrow =
            qbuf + ((size_t)bb * 2048 + q0 + qsub * 32 + l32) * 128 + hi8;
#pragma unroll
        for (int kc = 0; kc < 8; kc++)
            qf[kc] = *(const half8_t*)(qrow + kc * 16);
    }

    const _Float16* kbase = kbuf + ((size_t)bb * 2048 + g * 1024) * 128;
    const _Float16* vbase = vtbuf + (size_t)bb * 128 * 2048 + g * 1024;

    int tg = tid & 255;                           // thread within kv-group
    int krow = tg >> 2, kcol = (tg & 3) * 32;     // K stage: 64 x 128
    int vrow = tg >> 1, vcol = (tg & 1) * 32;     // V stage: 128 x 64

    // prologue: stage tile 0 into buffer A
    {
        const half8_t* ks = (const half8_t*)(kbase + (size_t)krow * 128 + kcol);
        half8_t k0 = ks[0], k1 = ks[1], k2 = ks[2], k3 = ks[3];
        const half8_t* vs = (const half8_t*)(vbase + (size_t)vrow * 2048 + vcol);
        half8_t v0 = vs[0], v1 = vs[1], v2 = vs[2], v3 = vs[3];
        *(half8_t*)&KsA[krow * 136 + kcol]      = k0;
        *(half8_t*)&KsA[krow * 136 + kcol + 8]  = k1;
        *(half8_t*)&KsA[krow * 136 + kcol + 16] = k2;
        *(half8_t*)&KsA[krow * 136 + kcol + 24] = k3;
        *(half8_t*)&VsA[vrow * 72 + vcol]       = v0;
        *(half8_t*)&VsA[vrow * 72 + vcol + 8]   = v1;
        *(half8_t*)&VsA[vrow * 72 + vcol + 16]  = v2;
        *(half8_t*)&VsA[vrow * 72 + vcol + 24]  = v3;
    }
    __syncthreads();

    f32x16 acc0 = {}, acc1 = {}, acc2 = {}, acc3 = {};
    float m = -INFINITY, l = 0.0f;

    for (int it = 0; it < 16; ++it) {
        bool more = it < 15;
        half8_t nk0, nk1, nk2, nk3, nv0, nv1, nv2, nv3;
        if (more) {   // T14: issue next-tile loads before compute
            const half8_t* ks =
                (const half8_t*)(kbase + (size_t)((it + 1) * 64 + krow) * 128 + kcol);
            nk0 = ks[0]; nk1 = ks[1]; nk2 = ks[2]; nk3 = ks[3];
            const half8_t* vs =
                (const half8_t*)(vbase + (size_t)vrow * 2048 + (it + 1) * 64 + vcol);
            nv0 = vs[0]; nv1 = vs[1]; nv2 = vs[2]; nv3 = vs[3];
        }

        // S^T[key][q] = K Q^T for this wave's 32 keys (kt subtile)
        f32x16 sf = {};
        __builtin_amdgcn_s_setprio(1);
#pragma unroll
        for (int kc = 0; kc < 8; kc++) {
            half8_t kf =
                *(const half8_t*)&KsA[(kt * 32 + l32) * 136 + kc * 16 + hi8];
            sf = MFMA32(kf, qf[kc], sf);
        }
        __builtin_amdgcn_s_setprio(0);

        // online softmax; q = l32 per lane; keys split across hi halves
        float mx = sf[0];
#pragma unroll
        for (int i = 1; i < 16; i++) mx = fmaxf(mx, sf[i]);
        mx = fmaxf(mx, __shfl_xor(mx, 32, 64));
        if (!__all(mx <= m + 8.0f)) {   // T13 defer-max (THR=8)
            float mn = fmaxf(m, mx);
            float al = exp2f(m - mn);
            l *= al;
            acc0 *= al; acc1 *= al; acc2 *= al; acc3 *= al;
            m = mn;
        }
        float p[16];
        float rs = 0.0f;
#pragma unroll
        for (int i = 0; i < 16; i++) {
            p[i] = exp2f(sf[i] - m);
            rs += p[i];
        }
        rs += __shfl_xor(rs, 32, 64);
        l += rs;

        // pack P (key = (r&3)+8*(r>>2)+4*hi), cross-hi exchange -> B-frags
        unsigned int u0 = pkh(p[0], p[1]),   u1 = pkh(p[2], p[3]);
        unsigned int u2 = pkh(p[4], p[5]),   u3 = pkh(p[6], p[7]);
        unsigned int u4 = pkh(p[8], p[9]),   u5 = pkh(p[10], p[11]);
        unsigned int u6 = pkh(p[12], p[13]), u7 = pkh(p[14], p[15]);
        unsigned int x00 = hi ? u0 : u2, x01 = hi ? u1 : u3;
        unsigned int x10 = hi ? u4 : u6, x11 = hi ? u5 : u7;
        unsigned int r00 = __shfl_xor(x00, 32, 64), r01 = __shfl_xor(x01, 32, 64);
        unsigned int r10 = __shfl_xor(x10, 32, 64), r11 = __shfl_xor(x11, 32, 64);
        uint32x4 b0u, b1u;
        b0u[0] = hi ? r00 : u0; b0u[1] = hi ? r01 : u1;
        b0u[2] = hi ? u2 : r00; b0u[3] = hi ? u3 : r01;
        b1u[0] = hi ? r10 : u4; b1u[1] = hi ? r11 : u5;
        b1u[2] = hi ? u6 : r10; b1u[3] = hi ? u7 : r11;
        half8_t pb0 = __builtin_bit_cast(half8_t, b0u);
        half8_t pb1 = __builtin_bit_cast(half8_t, b1u);

        // O^T[d][q] += V^T P^T  (A = V^T rows d, B = P^T cols q)
        __builtin_amdgcn_s_setprio(1);
        {
            half8_t v0 = *(const half8_t*)&VsA[(0 * 32 + l32) * 72 + kt * 32 + hi8];
            acc0 = MFMA32(v0, pb0, acc0);
            half8_t v1 = *(const half8_t*)&VsA[(0 * 32 + l32) * 72 + kt * 32 + 16 + hi8];
            acc0 = MFMA32(v1, pb1, acc0);
            half8_t v2 = *(const half8_t*)&VsA[(1 * 32 + l32) * 72 + kt * 32 + hi8];
            acc1 = MFMA32(v2, pb0, acc1);
            half8_t v3 = *(const half8_t*)&VsA[(1 * 32 + l32) * 72 + kt * 32 + 16 + hi8];
            acc1 = MFMA32(v3, pb1, acc1);
            half8_t v4 = *(const half8_t*)&VsA[(2 * 32 + l32) * 72 + kt * 32 + hi8];
            acc2 = MFMA32(v4, pb0, acc2);
            half8_t v5 = *(const half8_t*)&VsA[(2 * 32 + l32) * 72 + kt * 32 + 16 + hi8];
            acc2 = MFMA32(v5, pb1, acc2);
            half8_t v6 = *(const half8_t*)&VsA[(3 * 32 + l32) * 72 + kt * 32 + hi8];
            acc3 = MFMA32(v6, pb0, acc3);
            half8_t v7 = *(const half8_t*)&VsA[(3 * 32 + l32) * 72 + kt * 32 + 16 + hi8];
            acc3 = MFMA32(v7, pb1, acc3);
        }
        __builtin_amdgcn_s_setprio(0);

        if (more) {
            *(half8_t*)&KsB[krow * 136 + kcol]      = nk0;
            *(half8_t*)&KsB[krow * 136 + kcol + 8]  = nk1;
            *(half8_t*)&KsB[krow * 136 + kcol + 16] = nk2;
            *(half8_t*)&KsB[krow * 136 + kcol + 24] = nk3;
            *(half8_t*)&VsB[vrow * 72 + vcol]       = nv0;
            *(half8_t*)&VsB[vrow * 72 + vcol + 8]   = nv1;
            *(half8_t*)&VsB[vrow * 72 + vcol + 16]  = nv2;
            *(half8_t*)&VsB[vrow * 72 + vcol + 24]  = nv3;
        }
        __syncthreads();
        _Float16* tmp;
        tmp = KsA; KsA = KsB; KsB = tmp;
        tmp = VsA; VsA = VsB; VsB = tmp;
    }

    // -----------------------------------------------------------------------
    // Merge the 4 partial chains (g,kt) per qsub. Tree: kt-pairs, then g-pairs.
    // Scratch overlays dead K/V LDS: R1[4 regions][128][33] f32 + ml[4][64].
    // -----------------------------------------------------------------------
    float* R1 = (float*)smem;
    const int RS = 33;
    int wid2 = g * 2 + qsub;
    float* Om = R1 + wid2 * (128 * RS);
    float* Ml = R1 + 4 * 128 * RS + wid2 * 64;

#define STORE_ACC(DST, A, DT)                                             \
    {                                                                     \
        _Pragma("unroll") for (int r = 0; r < 16; r++) {                  \
            int d = (r & 3) + 8 * (r >> 2) + 4 * hi + 32 * (DT);          \
            (DST)[d * RS + l32] = (A)[r];                                 \
        }                                                                 \
    }
#define MERGE_ACC(SRC, A, DT)                                             \
    {                                                                     \
        _Pragma("unroll") for (int r = 0; r < 16; r++) {                  \
            int d = (r & 3) + 8 * (r >> 2) + 4 * hi + 32 * (DT);          \
            (A)[r] = (A)[r] * sa + (SRC)[d * RS + l32] * sb;              \
        }                                                                 \
    }

    if (kt == 1) {
        STORE_ACC(Om, acc0, 0); STORE_ACC(Om, acc1, 1);
        STORE_ACC(Om, acc2, 2); STORE_ACC(Om, acc3, 3);
        if (hi == 0) { Ml[l32] = m; Ml[32 + l32] = l; }
    }
    __syncthreads();
    if (kt == 0) {
        float m1 = Ml[l32], l1 = Ml[32 + l32];
        float mf = fmaxf(m, m1);
        float sa = exp2f(m - mf), sb = exp2f(m1 - mf);
        l = l * sa + l1 * sb;
        m = mf;
        MERGE_ACC(Om, acc0, 0); MERGE_ACC(Om, acc1, 1);
        MERGE_ACC(Om, acc2, 2); MERGE_ACC(Om, acc3, 3);
    }
    __syncthreads();
    if (kt == 0 && g == 1) {
        float* Om2 = R1 + qsub * (128 * RS);
        float* Ml2 = R1 + 4 * 128 * RS + qsub * 64;
        STORE_ACC(Om2, acc0, 0); STORE_ACC(Om2, acc1, 1);
        STORE_ACC(Om2, acc2, 2); STORE_ACC(Om2, acc3, 3);
        if (hi == 0) { Ml2[l32] = m; Ml2[32 + l32] = l; }
    }
    __syncthreads();
    if (kt == 0 && g == 0) {
        float* Om2 = R1 + qsub * (128 * RS);
        float* Ml2 = R1 + 4 * 128 * RS + qsub * 64;
        float m1 = Ml2[l32], l1 = Ml2[32 + l32];
        float mf = fmaxf(m, m1);
        float sa = exp2f(m - mf), sb = exp2f(m1 - mf);
        float lf = l * sa + l1 * sb;
        float inv = 1.0f / lf;
        float* op = out + ((size_t)bb * 2048 + q0 + qsub * 32 + l32) * 128;
#define FINAL_ACC(A, DT)                                                  \
        {                                                                 \
            _Pragma("unroll") for (int r = 0; r < 16; r++) {              \
                int d = (r & 3) + 8 * (r >> 2) + 4 * hi + 32 * (DT);      \
                op[d] = ((A)[r] * sa + Om2[d * RS + l32] * sb) * inv;     \
            }                                                             \
        }
        FINAL_ACC(acc0, 0); FINAL_ACC(acc1, 1);
        FINAL_ACC(acc2, 2); FINAL_ACC(acc3, 3);
#undef FINAL_ACC
    }
#undef STORE_ACC
#undef MERGE_ACC
}

// ---------------------------------------------------------------------------
extern "C" void kernel_launch(void* const* d_in, const int* in_sizes, int n_in,
                              void* d_out, int out_size, void* d_ws,
                              size_t ws_size, hipStream_t stream) {
    const float* q_in = (const float*)d_in[0];
    const float* k_in = (const float*)d_in[1];
    const float* v_in = (const float*)d_in[2];
    const float* Wq = (const float*)d_in[3];
    const float* Wk = (const float*)d_in[4];
    const float* Wv = (const float*)d_in[5];
    const float* bq = (const float*)d_in[6];
    const float* bk = (const float*)d_in[7];
    const float* bv = (const float*)d_in[8];
    float* out = (float*)d_out;

    char* ws = (char*)d_ws;
    _Float16* WtAll = (_Float16*)ws;                    // 3 * 65536 * 2 B
    _Float16* qbuf  = (_Float16*)(ws + 393216);         // 16384*128*2 = 4 MB
    _Float16* kbuf  = (_Float16*)(ws + 4587520);        // 4 MB
    _Float16* vtbuf = (_Float16*)(ws + 8781824);        // 4 MB (transposed)

    wt_kernel<<<dim3(256, 3), 256, 0, stream>>>(Wq, Wk, Wv, WtAll);
    proj_kernel<<<dim3(256, 3), 256, 0, stream>>>(q_in, k_in, v_in, WtAll, bq,
                                                  bk, bv, qbuf, kbuf, vtbuf);
    attn_kernel<<<dim3(256), 512, 0, stream>>>(qbuf, kbuf, vtbuf, out);
}